// Round 10
// baseline (363.696 us; speedup 1.0000x reference)
//
#include <hip/hip_runtime.h>
#include <hip/hip_bf16.h>
#include <math.h>

#define NHEADS 12
#define HEAD   64
#define DM     768
#define NB     256
#define SLEN   1024
#define NBATCH 8

typedef __bf16 bf16x8 __attribute__((ext_vector_type(8)));
typedef float  f32x4  __attribute__((ext_vector_type(4)));

// Flag semantics: 1 = inputs are bf16, 0 = inputs are fp32.
__device__ __forceinline__ float gload(const void* p, long i, int bf) {
  return bf ? __bfloat162float(((const __hip_bfloat16*)p)[i])
            : ((const float*)p)[i];
}

// ---------------------------------------------------------------------------
// Detect input dtype. bf16 N(0,1) data -> max|bf16| ~ 4; fp32 halves read as
// bf16 have uniform-random exponents -> astronomically large max.
// ---------------------------------------------------------------------------
__global__ void detect_dtype(const void* x, int* flag) {
  __shared__ float red[256];
  int t = threadIdx.x;
  const __hip_bfloat16* p = (const __hip_bfloat16*)x;
  float a = fabsf(__bfloat162float(p[t * 2]));
  float b = fabsf(__bfloat162float(p[t * 2 + 1]));
  float m = fmaxf(a, b);
  red[t] = m;
  __syncthreads();
  for (int s = 128; s > 0; s >>= 1) {
    if (t < s) red[t] = fmaxf(red[t], red[t + s]);
    __syncthreads();
  }
  if (t == 0) flag[0] = (red[0] < 1e4f) ? 1 : 0;
}

// ---------------------------------------------------------------------------
// Fused preprocessing: all independent convert/transpose/split work in ONE
// dispatch, block-range dispatched (see ranges below).
// Split scheme: a = ah + al (ah=bf16(a), al=bf16(a-ah)); al==0 when input bf16.
// ---------------------------------------------------------------------------
__global__ __launch_bounds__(256) void prep(
    const void* __restrict__ Wq, const void* __restrict__ Wk,
    const void* __restrict__ wmu, const void* __restrict__ wsig,
    const void* __restrict__ mub, const void* __restrict__ sigb,
    const void* __restrict__ G, const void* __restrict__ x,
    const void* __restrict__ Wv, const void* __restrict__ Wo,
    float* __restrict__ Wqf, float* __restrict__ Wkf,
    float* __restrict__ wmuf, float* __restrict__ wsigf,
    float* __restrict__ mubf, float* __restrict__ sigbf,
    __hip_bfloat16* __restrict__ Gth, __hip_bfloat16* __restrict__ Gtl,
    __hip_bfloat16* __restrict__ XCh, __hip_bfloat16* __restrict__ XCl,
    __hip_bfloat16* __restrict__ Wvh, __hip_bfloat16* __restrict__ Wvl,
    __hip_bfloat16* __restrict__ Woh, __hip_bfloat16* __restrict__ Wol,
    const int* __restrict__ flagp) {
  __shared__ float tl[64][65];
  const int blk = blockIdx.x, tid = threadIdx.x;
  const int bf = flagp[0];

  if (blk < 1152) {  // big converts
    const void* src = (blk < 576) ? Wq : Wk;
    float* dst = (blk < 576) ? Wqf : Wkf;
    int rb = (blk < 576) ? blk : blk - 576;
    int i0 = (rb * 256 + tid) * 4;
#pragma unroll
    for (int j = 0; j < 4; j++) dst[i0 + j] = gload(src, i0 + j, bf);
  } else if (blk < 1156) {  // small converts
    int which = blk - 1152;
    const void* src = (which == 0) ? wmu : (which == 1) ? wsig
                      : (which == 2) ? mub : sigb;
    float* dst = (which == 0) ? wmuf : (which == 1) ? wsigf
                 : (which == 2) ? mubf : sigbf;
    dst[tid] = gload(src, tid, bf);
  } else if (blk < 2756) {  // transpose+split (G or x)
    const void* src;
    __hip_bfloat16 *dh, *dl;
    int R = 1024, C, bx, by;
    if (blk < 1220) {
      int sub = blk - 1156;
      src = G; dh = Gth; dl = Gtl; C = 256; bx = sub % 4; by = sub / 4;
    } else {
      int sub = blk - 1220;
      src = x; dh = XCh; dl = XCl; C = 6144; bx = sub % 96; by = sub / 96;
    }
    int r0 = by * 64, c0 = bx * 64;
    int cl = tid & 63, rl = tid >> 6;
#pragma unroll
    for (int i = 0; i < 16; i++) {
      int rr = rl + i * 4;
      tl[rr][cl] = gload(src, (long)(r0 + rr) * C + c0 + cl, bf);
    }
    __syncthreads();
#pragma unroll
    for (int i = 0; i < 16; i++) {
      int cc = rl + i * 4;
      float f = tl[cl][cc];
      __hip_bfloat16 h = __float2bfloat16(f);
      long o = (long)(c0 + cc) * R + r0 + cl;
      dh[o] = h;
      dl[o] = __float2bfloat16(f - __bfloat162float(h));
    }
  } else {  // split4 Wv / Wo
    const void* src = (blk < 3332) ? Wv : Wo;
    __hip_bfloat16* dh = (blk < 3332) ? Wvh : Woh;
    __hip_bfloat16* dl = (blk < 3332) ? Wvl : Wol;
    int rb = (blk < 3332) ? blk - 2756 : blk - 3332;
    int i0 = (rb * 256 + tid) * 4;
#pragma unroll
    for (int j = 0; j < 4; j++) {
      float f = gload(src, i0 + j, bf);
      __hip_bfloat16 h = __float2bfloat16(f);
      dh[i0 + j] = h;
      dl[i0 + j] = __float2bfloat16(f - __bfloat162float(h));
    }
  }
}

// ---------------------------------------------------------------------------
// Fused-pass MFMA NT GEMM. 512 threads = 8 waves (2x4), tile 128x128, wave
// tile 64x32 (4x2 frags), BK=32, double-buffered LDS (3 slots x 2 = 48 KB).
// Per K-step, stage {A-hi, W, A-lo?} ONCE and issue both split-passes' MFMAs
// behind a single barrier (halves barriers + W-traffic vs sequential passes).
//   flag==1: 1 round: Ah*Wh [+ Al*Wh if pmask bit2]   (lo of bf16 inputs = 0)
//   flag==0: 2 rounds: {Ah*Wh + Ah*Wl}, then {Al*Wh}  (full 3-combo split)
// LDS XOR-swizzle (both-sides, rule #21): global_load_lds writes linearly;
// the SOURCE col granule is inverse-swizzled ((t&3)^((t>>3)&3)) and the frag
// read applies slot = g ^ ((row>>1)&3) -> phase bank conflicts 8-way -> 2-way.
// ksplit>1: stream fp32 partials to slab kc (no atomics, no zero-init).
// C/D mapping: col=lane&15, row=(lane>>4)*4+reg (HW-verified).
// ---------------------------------------------------------------------------
__device__ __forceinline__ void stage512(
    const __hip_bfloat16* __restrict__ src, int ld, __hip_bfloat16* lds, int t) {
  int row = t >> 2;
  int col = ((t & 3) ^ ((t >> 3) & 3)) * 8;  // inverse-swizzled global source
  const __hip_bfloat16* gp = src + (long)row * ld + col;
  __builtin_amdgcn_global_load_lds(
      (const __attribute__((address_space(1))) void*)gp,
      (__attribute__((address_space(3))) void*)((char*)lds + (t >> 6) * 1024),
      16, 0, 0);
}

__device__ __forceinline__ bf16x8 frag_read(
    const __hip_bfloat16* slot, int row, int g) {
  int sl = g ^ ((row >> 1) & 3);  // swizzled granule
  return *(const bf16x8*)(slot + row * 32 + sl * 8);
}

__global__ __launch_bounds__(512) void mfma_nt_lds(
    const __hip_bfloat16* __restrict__ Ah_g, const __hip_bfloat16* __restrict__ Al_g,
    const __hip_bfloat16* __restrict__ Wh_g, const __hip_bfloat16* __restrict__ Wl_g,
    void* __restrict__ Cout, int K, int lda, int ldb, long a_batch, long c_batch,
    int om, int oh, const int* __restrict__ flagp, int use_flag, int pmask_bf,
    int ksplit, long kslab) {
  int flag = flagp[0];
  int bf = use_flag ? flag : 0;
  __shared__ __hip_bfloat16 S[2][3][4096];  // [buf][slot: A, W, X][128x32]

  // Bijective XCD-aware swizzle (all launches here have nwg % 8 == 0).
  const int gx = gridDim.x, gy = gridDim.y;
  const int nwg = gx * gy * gridDim.z;
  const int lin = (blockIdx.z * gy + blockIdx.y) * gx + blockIdx.x;
  const int swz = (lin & 7) * (nwg >> 3) + (lin >> 3);
  const int bx = swz % gx;
  const int rem = swz / gx;
  const int by = rem % gy;
  const int bzf = rem / gy;
  const int bz = bzf / ksplit;          // batch index
  const int kc = bzf - bz * ksplit;     // K-chunk index
  const int Ks = K / ksplit;
  const int kbeg = kc * Ks, kend = kbeg + Ks;

  const int m0 = by * 128, n0 = bx * 128;
  const int t = threadIdx.x;
  const int lane = t & 63;
  const int r = lane & 15, g = lane >> 4;
  const int wave = t >> 6;
  const int wm = (wave >> 2) * 64, wn = (wave & 3) * 32;

  const __hip_bfloat16* AhR = Ah_g + (long)bz * a_batch + (long)m0 * lda;
  const __hip_bfloat16* AlR = Al_g + (long)bz * a_batch + (long)m0 * lda;
  const __hip_bfloat16* WhR = Wh_g + (long)n0 * ldb;
  const __hip_bfloat16* WlR = Wl_g + (long)n0 * ldb;

  f32x4 zero4 = {0.f, 0.f, 0.f, 0.f};
  f32x4 acc[4][2];
#pragma unroll
  for (int fi = 0; fi < 4; fi++)
#pragma unroll
    for (int fj = 0; fj < 2; fj++) acc[fi][fj] = zero4;

  // Round table. mode: 0 = A*W only; 1 = +X(second A)*W; 2 = +A*X(second W).
  int nrounds;
  const __hip_bfloat16 *rA[2], *rW[2], *rX[2];
  int rmode[2], rxld[2];
  if (flag) {
    nrounds = 1;
    rA[0] = AhR; rW[0] = WhR; rX[0] = AlR;
    rmode[0] = (pmask_bf & 4) ? 1 : 0; rxld[0] = lda;
  } else {
    nrounds = 2;
    rA[0] = AhR; rW[0] = WhR; rX[0] = WlR; rmode[0] = 2; rxld[0] = ldb;
    rA[1] = AlR; rW[1] = WhR; rX[1] = WhR; rmode[1] = 0; rxld[1] = ldb;
  }

  for (int rd = 0; rd < nrounds; rd++) {
    const __hip_bfloat16* A0 = rA[rd];
    const __hip_bfloat16* W0 = rW[rd];
    const __hip_bfloat16* X0 = rX[rd];
    const int md = rmode[rd], xld = rxld[rd];
    stage512(A0 + kbeg, lda, S[0][0], t);
    stage512(W0 + kbeg, ldb, S[0][1], t);
    if (md) stage512(X0 + kbeg, xld, S[0][2], t);
    __syncthreads();
    int cur = 0;
    for (int k0 = kbeg; k0 < kend; k0 += 32) {
      bf16x8 af[4], bw[2], xf[4];
#pragma unroll
      for (int fi = 0; fi < 4; fi++)
        af[fi] = frag_read(S[cur][0], wm + fi * 16 + r, g);
#pragma unroll
      for (int fj = 0; fj < 2; fj++)
        bw[fj] = frag_read(S[cur][1], wn + fj * 16 + r, g);
      if (md == 1) {
#pragma unroll
        for (int fi = 0; fi < 4; fi++)
          xf[fi] = frag_read(S[cur][2], wm + fi * 16 + r, g);
      } else if (md == 2) {
#pragma unroll
        for (int fj = 0; fj < 2; fj++)
          xf[fj] = frag_read(S[cur][2], wn + fj * 16 + r, g);
      }
      // Prefetch next K-step into the other buffer; loads progress under MFMA.
      if (k0 + 32 < kend) {
        stage512(A0 + k0 + 32, lda, S[cur ^ 1][0], t);
        stage512(W0 + k0 + 32, ldb, S[cur ^ 1][1], t);
        if (md) stage512(X0 + k0 + 32, xld, S[cur ^ 1][2], t);
      }
#pragma unroll
      for (int fi = 0; fi < 4; fi++)
#pragma unroll
        for (int fj = 0; fj < 2; fj++)
          acc[fi][fj] = __builtin_amdgcn_mfma_f32_16x16x32_bf16(
              af[fi], bw[fj], acc[fi][fj], 0, 0, 0);
      if (md == 1) {
#pragma unroll
        for (int fi = 0; fi < 4; fi++)
#pragma unroll
          for (int fj = 0; fj < 2; fj++)
            acc[fi][fj] = __builtin_amdgcn_mfma_f32_16x16x32_bf16(
                xf[fi], bw[fj], acc[fi][fj], 0, 0, 0);
      } else if (md == 2) {
#pragma unroll
        for (int fi = 0; fi < 4; fi++)
#pragma unroll
          for (int fj = 0; fj < 2; fj++)
            acc[fi][fj] = __builtin_amdgcn_mfma_f32_16x16x32_bf16(
                af[fi], xf[fj], acc[fi][fj], 0, 0, 0);
      }
      __syncthreads();
      cur ^= 1;
    }
  }

  if (ksplit > 1) {
    float* Cf = (float*)Cout + (long)kc * kslab;
#pragma unroll
    for (int fi = 0; fi < 4; fi++)
#pragma unroll
      for (int fj = 0; fj < 2; fj++)
#pragma unroll
        for (int v = 0; v < 4; v++) {
          int m = m0 + wm + fi * 16 + g * 4 + v;
          int n = n0 + wn + fj * 16 + r;
          long off = (long)bz * c_batch + (long)m * om + (long)(n >> 6) * oh + (n & 63);
          Cf[off] = acc[fi][fj][v];  // streaming partial, no RMW
        }
  } else {
#pragma unroll
    for (int fi = 0; fi < 4; fi++)
#pragma unroll
      for (int fj = 0; fj < 2; fj++)
#pragma unroll
        for (int v = 0; v < 4; v++) {
          int m = m0 + wm + fi * 16 + g * 4 + v;  // row = (lane>>4)*4 + reg
          int n = n0 + wn + fj * 16 + r;          // col = lane&15
          long off = (long)bz * c_batch + (long)m * om + (long)(n >> 6) * oh + (n & 63);
          float val = acc[fi][fj][v];
          if (bf) ((__hip_bfloat16*)Cout)[off] = __float2bfloat16(val);
          else    ((float*)Cout)[off] = val;
        }
  }
}

// ---------------------------------------------------------------------------
// Reduce 4 fp32 slabs -> Bmat fp32 + split-bf16 Bh/Bl. Vectorized x4.
// ---------------------------------------------------------------------------
__global__ __launch_bounds__(256) void reduce_split(
    const float* __restrict__ slabs, float* __restrict__ outf,
    __hip_bfloat16* __restrict__ dh, __hip_bfloat16* __restrict__ dl) {
  long i0 = ((long)blockIdx.x * 256 + threadIdx.x) * 4;
  f32x4 s = *(const f32x4*)(slabs + i0);
#pragma unroll
  for (int k = 1; k < 4; k++) {
    f32x4 v = *(const f32x4*)(slabs + (long)k * 1572864 + i0);
    s.x += v.x; s.y += v.y; s.z += v.z; s.w += v.w;
  }
  *(f32x4*)(outf + i0) = s;
#pragma unroll
  for (int j = 0; j < 4; j++) {
    float f = s[j];
    __hip_bfloat16 h = __float2bfloat16(f);
    dh[i0 + j] = h;
    dl[i0 + j] = __float2bfloat16(f - __bfloat162float(h));
  }
}

// ---------------------------------------------------------------------------
// Reduce 4 value-slabs [B,H,256,64] -> V^T split bf16 [B,H,64,256].
// ---------------------------------------------------------------------------
__global__ __launch_bounds__(256) void vtsplit_sum(
    const float* __restrict__ slabs, __hip_bfloat16* __restrict__ dh,
    __hip_bfloat16* __restrict__ dl) {
  __shared__ float tle[64][65];
  const int z = blockIdx.y;        // 96 = B*H
  const int r0 = blockIdx.x * 64;  // 4 row-tiles over n=256
  int cl = threadIdx.x & 63, rl4 = threadIdx.x >> 6;
#pragma unroll
  for (int i = 0; i < 16; i++) {
    int rr = rl4 + i * 4;
    long idx = (long)z * 16384 + (r0 + rr) * 64 + cl;
    float s = slabs[idx];
#pragma unroll
    for (int k = 1; k < 4; k++) s += slabs[(long)k * 1572864 + idx];
    tle[rr][cl] = s;
  }
  __syncthreads();
#pragma unroll
  for (int i = 0; i < 16; i++) {
    int cc = rl4 + i * 4;          // d index
    float f = tle[cl][cc];         // = V[n=r0+cl][d=cc]
    __hip_bfloat16 h = __float2bfloat16(f);
    long o = (long)z * 16384 + (long)cc * 256 + r0 + cl;
    dh[o] = h;
    dl[o] = __float2bfloat16(f - __bfloat162float(h));
  }
}

// ---------------------------------------------------------------------------
// bmu[b,d] = sum_n w_mu[n] * Bmat[n, b*768+d]   (and bsig with w_sigma)
// ---------------------------------------------------------------------------
__global__ __launch_bounds__(256) void bvec(
    const float* __restrict__ Bmat, const float* __restrict__ wmuf,
    const float* __restrict__ wsigf, float* __restrict__ bmu,
    float* __restrict__ bsig) {
  int t = blockIdx.x * 256 + threadIdx.x;
  int w = t / 6144, r = t % 6144;
  const float* wv = w ? wsigf : wmuf;
  float acc = 0.f;
  for (int n = 0; n < NB; n++) acc += wv[n] * Bmat[(long)n * 6144 + r];
  (w ? bsig : bmu)[r] = acc;
}

// kmu[b,c] = sum_d bmu[b,d] * Wk[c,d]   (c = h*64+dh), and ksig with bsig.
__global__ __launch_bounds__(256) void kvec(
    const float* __restrict__ Wkf, const float* __restrict__ bmu,
    const float* __restrict__ bsig, float* __restrict__ kmu,
    float* __restrict__ ksig) {
  int t = blockIdx.x * 256 + threadIdx.x;
  int w = t / 6144, r = t % 6144;
  int b = r / 768, c = r % 768;
  const float* bv = (w ? bsig : bmu) + b * 768;
  const float* wk = Wkf + (long)c * 768;
  float acc = 0.f;
  for (int d = 0; d < 768; d++) acc += bv[d] * wk[d];
  (w ? ksig : kmu)[r] = acc;
}

// wqm[b,h,d] = sum_dh Wq[h*64+dh, d] * kmu[b, h*64+dh]   (and wqs with ksig)
__global__ __launch_bounds__(256) void wqvec(
    const float* __restrict__ Wqf, const float* __restrict__ kmu,
    const float* __restrict__ ksig, float* __restrict__ wqm,
    float* __restrict__ wqs) {
  int t = blockIdx.x * 256 + threadIdx.x;
  int w = t / 73728, r = t % 73728;
  int b = r / 9216, h = (r % 9216) / 768, d = r % 768;
  const float* kv = (w ? ksig : kmu) + b * 768 + h * 64;
  float acc = 0.f;
  for (int dh = 0; dh < 64; dh++)
    acc += Wqf[(long)(h * 64 + dh) * 768 + d] * kv[dh];
  (w ? wqs : wqm)[r] = acc;
}

// ---------------------------------------------------------------------------
// amu[b, hh, qrow] = dot768(q[qrow, b, :], wq{m|s}[b, hh, :]); one wave/q-row.
// ---------------------------------------------------------------------------
__global__ __launch_bounds__(256) void amu_kernel(
    const void* __restrict__ q, const float* __restrict__ wqm,
    const float* __restrict__ wqs, float* __restrict__ amu,
    const int* __restrict__ flagp) {
  int bf = flagp[0];
  int lane = threadIdx.x & 63;
  int wave = threadIdx.x >> 6;
  int qrow = blockIdx.x * 4 + wave;
  int b = blockIdx.y;
  float qv[12];
  long base = ((long)qrow * 8 + b) * 768 + lane;
#pragma unroll
  for (int j = 0; j < 12; j++) qv[j] = gload(q, base + 64 * j, bf);
  for (int hh = 0; hh < 24; hh++) {
    const float* vec = (hh < 12) ? (wqm + ((long)b * 12 + hh) * 768)
                                 : (wqs + ((long)b * 12 + hh - 12) * 768);
    float p = 0.f;
#pragma unroll
    for (int j = 0; j < 12; j++) p += qv[j] * vec[lane + 64 * j];
#pragma unroll
    for (int m = 32; m >= 1; m >>= 1) p += __shfl_xor(p, m);
    if (lane == 0) amu[((long)b * 24 + hh) * 1024 + qrow] = p;
  }
}

// ---------------------------------------------------------------------------
// Fused MFMA attention: ctx[q,d] = sum_n r(q,n) * V[n,d] per (b,h).
// A = R computed in-register (split rh/rl), B = V^T (pre-split bf16 h/l).
// Wave tile: 32 q (fi=0,1) x 64 d (fj=0..3), K = 256 n in 8 k-steps.
// ---------------------------------------------------------------------------
__global__ __launch_bounds__(256) void attn_mfma(
    const __hip_bfloat16* __restrict__ Vth, const __hip_bfloat16* __restrict__ Vtl,
    const float* __restrict__ amu, const float* __restrict__ mubf,
    const float* __restrict__ sigbf, __hip_bfloat16* __restrict__ Ch,
    __hip_bfloat16* __restrict__ Cl) {
  const int qch = blockIdx.x, h = blockIdx.y, b = blockIdx.z;
  const int t = threadIdx.x;
  const int lane = t & 63, wave = t >> 6;
  const int r = lane & 15, g = lane >> 4;
  const int wq = wave * 32;
  __shared__ float s_mub[NB], s_sb2[NB];
  {
    float sb = sigbf[t];
    s_mub[t] = mubf[t];
    s_sb2[t] = sb * sb;
  }
  __syncthreads();

  float mu_[2], sig_[2];
#pragma unroll
  for (int fi = 0; fi < 2; fi++) {
    int q = qch * 128 + wq + fi * 16 + r;
    float araw = amu[((long)b * 24 + h) * 1024 + q] * 0.125f;
    float sraw = amu[((long)b * 24 + 12 + h) * 1024 + q] * 0.125f;
    mu_[fi] = 1.f / (1.f + expf(-araw));
    sig_[fi] = fmaxf(sraw, 0.f) + log1pf(expf(-fabsf(sraw)));  // softplus
  }

  const __hip_bfloat16* vhb = Vth + ((long)b * 12 + h) * 16384;
  const __hip_bfloat16* vlb = Vtl + ((long)b * 12 + h) * 16384;

  f32x4 zero4 = {0.f, 0.f, 0.f, 0.f};
  f32x4 acc[2][4];
#pragma unroll
  for (int fi = 0; fi < 2; fi++)
#pragma unroll
    for (int fj = 0; fj < 4; fj++) acc[fi][fj] = zero4;

  for (int ks = 0; ks < 8; ks++) {
    bf16x8 rh[2], rl[2];
#pragma unroll
    for (int fi = 0; fi < 2; fi++) {
      float mu = mu_[fi], sg = sig_[fi];
#pragma unroll
      for (int j = 0; j < 8; j++) {
        int n = ks * 32 + g * 8 + j;
        float inv_s = rsqrtf(s_sb2[n] + sg);
        float tt = (mu - s_mub[n]) * inv_s;
        float rv = 0.3989422804014327f * inv_s *
                   exp2f(-0.7213475204444817f * tt * tt);
        __bf16 hi = (__bf16)rv;
        rh[fi][j] = hi;
        rl[fi][j] = (__bf16)(rv - (float)hi);
      }
    }
#pragma unroll
    for (int fj = 0; fj < 4; fj++) {
      long vo = (long)(fj * 16 + r) * 256 + ks * 32 + g * 8;
      bf16x8 vh = *(const bf16x8*)(vhb + vo);
      bf16x8 vl = *(const bf16x8*)(vlb + vo);
#pragma unroll
      for (int fi = 0; fi < 2; fi++) {
        acc[fi][fj] = __builtin_amdgcn_mfma_f32_16x16x32_bf16(
            rh[fi], vh, acc[fi][fj], 0, 0, 0);
        acc[fi][fj] = __builtin_amdgcn_mfma_f32_16x16x32_bf16(
            rl[fi], vh, acc[fi][fj], 0, 0, 0);
        acc[fi][fj] = __builtin_amdgcn_mfma_f32_16x16x32_bf16(
            rh[fi], vl, acc[fi][fj], 0, 0, 0);
      }
    }
  }

#pragma unroll
  for (int fi = 0; fi < 2; fi++)
#pragma unroll
    for (int fj = 0; fj < 4; fj++)
#pragma unroll
      for (int v = 0; v < 4; v++) {
        int q = qch * 128 + wq + fi * 16 + g * 4 + v;  // row = (lane>>4)*4+reg
        int d = fj * 16 + r;                            // col = lane&15
        long off = ((long)(b * SLEN + q)) * DM + h * HEAD + d;
        float f = acc[fi][fj][v];
        __hip_bfloat16 hh = __float2bfloat16(f);
        Ch[off] = hh;
        Cl[off] = __float2bfloat16(f - __bfloat162float(hh));
      }
}

// ---------------------------------------------------------------------------
extern "C" void kernel_launch(void* const* d_in, const int* in_sizes, int n_in,
                              void* d_out, int out_size, void* d_ws, size_t ws_size,
                              hipStream_t stream) {
  const void* x    = d_in[0];
  const void* q    = d_in[1];
  const void* Wq   = d_in[2];
  const void* Wk   = d_in[3];
  const void* Wv   = d_in[4];
  const void* Wo   = d_in[5];
  const void* wmu  = d_in[6];
  const void* wsig = d_in[7];
  const void* mub  = d_in[8];
  const void* sigb = d_in[9];
  const void* G    = d_in[10];

  int* flagp = (int*)d_ws;
  float* base = (float*)d_ws + 16;
  float* Wqf   = base;              // 589824
  float* Wkf   = Wqf + 589824;      // 589824
  float* wmuf  = Wkf + 589824;      // 256
  float* wsigf = wmuf + 256;        // 256
  float* mubf  = wsigf + 256;       // 256
  float* sigbf = mubf + 256;        // 256
  float* Bmat  = sigbf + 256;       // 1572864  [256, 6144] fp32
  float* slab1 = Bmat + 1572864;    // 6291456  4x[256,6144] fp32 GEMM1 partials
  float* wqm   = slab1 + 6291456;   // 73728
  float* wqs   = wqm + 73728;       // 73728
  float* amu   = wqs + 73728;       // 196608  [B,24,1024]
  float* bmu   = amu + 196608;      // 6144
  float* bsig  = bmu + 6144;        // 6144
  float* kmu   = bsig + 6144;       // 6144
  float* ksig  = kmu + 6144;        // 6144
  // bf16 arrays (all 16B-aligned)
  __hip_bfloat16* Wvh = (__hip_bfloat16*)(ksig + 6144);   // 589824
  __hip_bfloat16* Wvl = Wvh + 589824;   // 589824
  __hip_bfloat16* Woh = Wvl + 589824;   // 589824
  __hip_bfloat16* Wol = Woh + 589824;   // 589824
  __hip_bfloat16* Gth = Wol + 589824;   // 262144  [256,1024]
  __hip_bfloat16* Gtl = Gth + 262144;   // 262144
  __hip_bfloat16* Bh  = Gtl + 262144;   // 1572864 [256,6144]
  __hip_bfloat16* Bl  = Bh + 1572864;   // 1572864
  // XCh/XCl region (25.2 MB) serves three consecutive roles:
  //   1) x^T split [6144,1024] for GEMM1
  //   2) GEMM2 fp32 partial slabs 4x[B,H,256,64] (= exactly 6291456 floats)
  //   3) ctx split-bf16 [8192,768] written by attn for GEMM3
  __hip_bfloat16* XCh = Bl + 1572864;   // 6291456
  __hip_bfloat16* XCl = XCh + 6291456;  // 6291456
  float* slab2 = (float*)XCh;           // alias, role 2
  __hip_bfloat16* Vth = XCl + 6291456;  // 1572864 [B,H,64,256] split V^T
  __hip_bfloat16* Vtl = Vth + 1572864;  // 1572864
  // total ~81 MB

  detect_dtype<<<1, 256, 0, stream>>>(x, flagp);

  // All independent preprocessing in one dispatch.
  prep<<<3908, 256, 0, stream>>>(
      Wq, Wk, wmu, wsig, mub, sigb, G, x, Wv, Wo,
      Wqf, Wkf, wmuf, wsigf, mubf, sigbf,
      Gth, Gtl, XCh, XCl, Wvh, Wvl, Woh, Wol, flagp);

  // GEMM1: Bmat = G^T @ x^T'; M=256 N=6144 K=1024. ksplit=4 streamed slabs.
  mfma_nt_lds<<<dim3(48, 2, 4), 512, 0, stream>>>(
      Gth, Gtl, XCh, XCl, slab1, /*K=*/1024, /*lda=*/1024, /*ldb=*/1024,
      /*a_batch=*/0, /*c_batch=*/0, /*om=*/6144, /*oh=*/64, flagp, 0,
      /*pmask_bf=*/1, /*ksplit=*/4, /*kslab=*/1572864);

  // slabs -> Bmat fp32 + Bh/Bl split (one pass).
  reduce_split<<<1536, 256, 0, stream>>>(slab1, Bmat, Bh, Bl);

  // GEMM2: values(z) = Bmat_z @ Wv^T; ksplit=4 streamed slabs (into XC region;
  // x^T is dead after GEMM1).
  mfma_nt_lds<<<dim3(6, 2, 32), 512, 0, stream>>>(
      Bh, Bl, Wvh, Wvl, slab2, /*K=*/768, /*lda=*/6144, /*ldb=*/768,
      /*a_batch=*/768, /*c_batch=*/196608, /*om=*/64, /*oh=*/16384, flagp, 0,
      /*pmask_bf=*/5, /*ksplit=*/4, /*kslab=*/1572864);

  // slabs -> V^T split (one pass; fp32 values never materialized).
  vtsplit_sum<<<dim3(4, 96), 256, 0, stream>>>(slab2, Vth, Vtl);

  // collapse chain as 3 separate well-parallelized kernels (48/48/576 blocks;
  // the 16-block fused version was a 380 µs occupancy disaster — R6).
  bvec<<<48, 256, 0, stream>>>(Bmat, wmuf, wsigf, bmu, bsig);
  kvec<<<48, 256, 0, stream>>>(Wkf, bmu, bsig, kmu, ksig);
  wqvec<<<576, 256, 0, stream>>>(Wqf, kmu, ksig, wqm, wqs);
  amu_kernel<<<dim3(256, 8), 256, 0, stream>>>(q, wqm, wqs, amu, flagp);

  // fused MFMA attention -> ctx split-bf16 [8192,768] (into XCh/XCl; slab2
  // already consumed by vtsplit_sum).
  attn_mfma<<<dim3(8, 12, 8), 256, 0, stream>>>(
      Vth, Vtl, amu, mubf, sigbf, XCh, XCl);

  // GEMM3: out = ctx @ Wo^T; M=8192 N=768 K=768; direct store (dtype per flag).
  mfma_nt_lds<<<dim3(6, 64, 1), 512, 0, stream>>>(
      XCh, XCl, Woh, Wol, d_out, /*K=*/768, /*lda=*/768, /*ldb=*/768,
      /*a_batch=*/0, /*c_batch=*/0, /*om=*/768, /*oh=*/64, flagp, 1,
      /*pmask_bf=*/5, /*ksplit=*/1, /*kslab=*/0);
}

// Round 12
// 340.145 us; speedup vs baseline: 1.0692x; 1.0692x over previous
//
#include <hip/hip_runtime.h>
#include <hip/hip_bf16.h>
#include <math.h>

#define NHEADS 12
#define HEAD   64
#define DM     768
#define NB     256
#define SLEN   1024
#define NBATCH 8

typedef __bf16 bf16x8 __attribute__((ext_vector_type(8)));
typedef float  f32x4  __attribute__((ext_vector_type(4)));

// Flag semantics: 1 = inputs are bf16, 0 = inputs are fp32.
__device__ __forceinline__ float gload(const void* p, long i, int bf) {
  return bf ? __bfloat162float(((const __hip_bfloat16*)p)[i])
            : ((const float*)p)[i];
}

// ---------------------------------------------------------------------------
// Detect input dtype. bf16 N(0,1) data -> max|bf16| ~ 4; fp32 halves read as
// bf16 have uniform-random exponents -> astronomically large max.
// ---------------------------------------------------------------------------
__global__ void detect_dtype(const void* x, int* flag) {
  __shared__ float red[256];
  int t = threadIdx.x;
  const __hip_bfloat16* p = (const __hip_bfloat16*)x;
  float a = fabsf(__bfloat162float(p[t * 2]));
  float b = fabsf(__bfloat162float(p[t * 2 + 1]));
  float m = fmaxf(a, b);
  red[t] = m;
  __syncthreads();
  for (int s = 128; s > 0; s >>= 1) {
    if (t < s) red[t] = fmaxf(red[t], red[t + s]);
    __syncthreads();
  }
  if (t == 0) flag[0] = (red[0] < 1e4f) ? 1 : 0;
}

// ---------------------------------------------------------------------------
// Fused preprocessing: all independent convert/transpose/split work in ONE
// dispatch, block-range dispatched (see ranges below).
// Split scheme: a = ah + al (ah=bf16(a), al=bf16(a-ah)); al==0 when input bf16.
// ---------------------------------------------------------------------------
__global__ __launch_bounds__(256) void prep(
    const void* __restrict__ Wq, const void* __restrict__ Wk,
    const void* __restrict__ wmu, const void* __restrict__ wsig,
    const void* __restrict__ mub, const void* __restrict__ sigb,
    const void* __restrict__ G, const void* __restrict__ x,
    const void* __restrict__ Wv, const void* __restrict__ Wo,
    float* __restrict__ Wqf, float* __restrict__ Wkf,
    float* __restrict__ wmuf, float* __restrict__ wsigf,
    float* __restrict__ mubf, float* __restrict__ sigbf,
    __hip_bfloat16* __restrict__ Gth, __hip_bfloat16* __restrict__ Gtl,
    __hip_bfloat16* __restrict__ XCh, __hip_bfloat16* __restrict__ XCl,
    __hip_bfloat16* __restrict__ Wvh, __hip_bfloat16* __restrict__ Wvl,
    __hip_bfloat16* __restrict__ Woh, __hip_bfloat16* __restrict__ Wol,
    const int* __restrict__ flagp) {
  __shared__ float tl[64][65];
  const int blk = blockIdx.x, tid = threadIdx.x;
  const int bf = flagp[0];

  if (blk < 1152) {  // big converts
    const void* src = (blk < 576) ? Wq : Wk;
    float* dst = (blk < 576) ? Wqf : Wkf;
    int rb = (blk < 576) ? blk : blk - 576;
    int i0 = (rb * 256 + tid) * 4;
#pragma unroll
    for (int j = 0; j < 4; j++) dst[i0 + j] = gload(src, i0 + j, bf);
  } else if (blk < 1156) {  // small converts
    int which = blk - 1152;
    const void* src = (which == 0) ? wmu : (which == 1) ? wsig
                      : (which == 2) ? mub : sigb;
    float* dst = (which == 0) ? wmuf : (which == 1) ? wsigf
                 : (which == 2) ? mubf : sigbf;
    dst[tid] = gload(src, tid, bf);
  } else if (blk < 2756) {  // transpose+split (G or x)
    const void* src;
    __hip_bfloat16 *dh, *dl;
    int R = 1024, C, bx, by;
    if (blk < 1220) {
      int sub = blk - 1156;
      src = G; dh = Gth; dl = Gtl; C = 256; bx = sub % 4; by = sub / 4;
    } else {
      int sub = blk - 1220;
      src = x; dh = XCh; dl = XCl; C = 6144; bx = sub % 96; by = sub / 96;
    }
    int r0 = by * 64, c0 = bx * 64;
    int cl = tid & 63, rl = tid >> 6;
#pragma unroll
    for (int i = 0; i < 16; i++) {
      int rr = rl + i * 4;
      tl[rr][cl] = gload(src, (long)(r0 + rr) * C + c0 + cl, bf);
    }
    __syncthreads();
#pragma unroll
    for (int i = 0; i < 16; i++) {
      int cc = rl + i * 4;
      float f = tl[cl][cc];
      __hip_bfloat16 h = __float2bfloat16(f);
      long o = (long)(c0 + cc) * R + r0 + cl;
      dh[o] = h;
      dl[o] = __float2bfloat16(f - __bfloat162float(h));
    }
  } else {  // split4 Wv / Wo
    const void* src = (blk < 3332) ? Wv : Wo;
    __hip_bfloat16* dh = (blk < 3332) ? Wvh : Woh;
    __hip_bfloat16* dl = (blk < 3332) ? Wvl : Wol;
    int rb = (blk < 3332) ? blk - 2756 : blk - 3332;
    int i0 = (rb * 256 + tid) * 4;
#pragma unroll
    for (int j = 0; j < 4; j++) {
      float f = gload(src, i0 + j, bf);
      __hip_bfloat16 h = __float2bfloat16(f);
      dh[i0 + j] = h;
      dl[i0 + j] = __float2bfloat16(f - __bfloat162float(h));
    }
  }
}

// ---------------------------------------------------------------------------
// Counted-vmcnt pipelined MFMA NT GEMM (T3/T4 minimum recipe, m201-style).
// 256 threads = 4 waves (2x2), tile 128x128, wave tile 64x64 (4x4 frags),
// BK=32, 2-deep ring of LDS buffers, 3 slots {A, W, X}: 48 KB total.
// Per K-step i:  s_waitcnt vmcnt(NS)  [stage(i+1) stays IN FLIGHT]
//                raw s_barrier        [buf i visible to all waves]
//                ds_read frags; lgkmcnt(0); sched_barrier; raw s_barrier
//                issue stage(i+2) into buf i  [flies under the MFMAs]
//                MFMA block
// NS = vm-instrs per stage per wave = 4 (2 slots) or 6 (3 slots). Loads are
// never drained to 0 inside the loop -- the drain-per-step was the invariant
// across R3/R4/R8/R10's identical ~60 us GEMM times (m233/m218 mechanism).
// Rounds (split-bf16): flag==1: 1 round {Ah*Wh [+Al*Wh]};
//                      flag==0: {Ah*Wh + Ah*Wl}, then {Al*Wh}.
// LDS XOR-swizzle as R10 (verified: conflicts -> 0), both-sides involution.
// ksplit>1 streams fp32 partials to per-chunk slabs (no atomics).
// C/D mapping: col=lane&15, row=(lane>>4)*4+reg (HW-verified).
// ---------------------------------------------------------------------------
__device__ __forceinline__ void stage256(
    const __hip_bfloat16* __restrict__ src, int ld, __hip_bfloat16* lds, int t) {
  int row = t >> 2;
  int col = ((t & 3) ^ ((t >> 3) & 3)) * 8;  // inverse-swizzled global source
  int wavebase = (t >> 6) * 1024;  // bytes
#pragma unroll
  for (int i = 0; i < 2; i++) {
    const __hip_bfloat16* gp = src + (long)(i * 64 + row) * ld + col;
    __builtin_amdgcn_global_load_lds(
        (const __attribute__((address_space(1))) void*)gp,
        (__attribute__((address_space(3))) void*)((char*)lds + i * 4096 + wavebase),
        16, 0, 0);
  }
}

__device__ __forceinline__ bf16x8 frag_read(
    const __hip_bfloat16* slot, int row, int g) {
  int sl = g ^ ((row >> 1) & 3);  // swizzled granule (involution w/ stage256)
  return *(const bf16x8*)(slot + row * 32 + sl * 8);
}

__global__ __launch_bounds__(256) void mfma_nt_lds(
    const __hip_bfloat16* __restrict__ Ah_g, const __hip_bfloat16* __restrict__ Al_g,
    const __hip_bfloat16* __restrict__ Wh_g, const __hip_bfloat16* __restrict__ Wl_g,
    void* __restrict__ Cout, int K, int lda, int ldb, long a_batch, long c_batch,
    int om, int oh, const int* __restrict__ flagp, int use_flag, int pmask_bf,
    int ksplit, long kslab) {
  int flag = flagp[0];
  int bf = use_flag ? flag : 0;
  __shared__ __hip_bfloat16 S[2][3][4096];  // [buf][slot: A, W, X][128x32]

  // Bijective XCD-aware swizzle (all launches here have nwg % 8 == 0).
  const int gx = gridDim.x, gy = gridDim.y;
  const int nwg = gx * gy * gridDim.z;
  const int lin = (blockIdx.z * gy + blockIdx.y) * gx + blockIdx.x;
  const int swz = (lin & 7) * (nwg >> 3) + (lin >> 3);
  const int bx = swz % gx;
  const int rem = swz / gx;
  const int by = rem % gy;
  const int bzf = rem / gy;
  const int bz = bzf / ksplit;          // batch index
  const int kc = bzf - bz * ksplit;     // K-chunk index
  const int Ks = K / ksplit;
  const int kbeg = kc * Ks;
  const int nk = Ks >> 5;               // K-steps (BK=32); >= 6 for all uses

  const int m0 = by * 128, n0 = bx * 128;
  const int t = threadIdx.x;
  const int lane = t & 63;
  const int r = lane & 15, g = lane >> 4;
  const int wave = t >> 6;
  const int wm = (wave >> 1) * 64, wn = (wave & 1) * 64;

  const __hip_bfloat16* AhR = Ah_g + (long)bz * a_batch + (long)m0 * lda;
  const __hip_bfloat16* AlR = Al_g + (long)bz * a_batch + (long)m0 * lda;
  const __hip_bfloat16* WhR = Wh_g + (long)n0 * ldb;
  const __hip_bfloat16* WlR = Wl_g + (long)n0 * ldb;

  f32x4 zero4 = {0.f, 0.f, 0.f, 0.f};
  f32x4 acc[4][4];
#pragma unroll
  for (int fi = 0; fi < 4; fi++)
#pragma unroll
    for (int fj = 0; fj < 4; fj++) acc[fi][fj] = zero4;

  // Round table. mode: 0 = A*W only; 1 = +X(second A)*W; 2 = +A*X(second W).
  // (flag is consumed by this branch BEFORE any staging -> vmcnt==0 at entry.)
  int nrounds;
  const __hip_bfloat16 *rA[2], *rW[2], *rX[2];
  int rmode[2], rxld[2];
  if (flag) {
    nrounds = 1;
    rA[0] = AhR; rW[0] = WhR; rX[0] = AlR;
    rmode[0] = (pmask_bf & 4) ? 1 : 0; rxld[0] = lda;
  } else {
    nrounds = 2;
    rA[0] = AhR; rW[0] = WhR; rX[0] = WlR; rmode[0] = 2; rxld[0] = ldb;
    rA[1] = AlR; rW[1] = WhR; rX[1] = WhR; rmode[1] = 0; rxld[1] = ldb;
  }

  for (int rd = 0; rd < nrounds; rd++) {
    const __hip_bfloat16* A0 = rA[rd];
    const __hip_bfloat16* W0 = rW[rd];
    const __hip_bfloat16* X0 = rX[rd];
    const int md = rmode[rd], xld = rxld[rd];
    // Prologue: stage steps 0 and 1 (outstanding = 2 tiles).
    stage256(A0 + kbeg, lda, S[0][0], t);
    stage256(W0 + kbeg, ldb, S[0][1], t);
    if (md) stage256(X0 + kbeg, xld, S[0][2], t);
    stage256(A0 + kbeg + 32, lda, S[1][0], t);
    stage256(W0 + kbeg + 32, ldb, S[1][1], t);
    if (md) stage256(X0 + kbeg + 32, xld, S[1][2], t);

    for (int i = 0; i < nk; i++) {
      // Wait for stage(i); leave stage(i+1) in flight (counted vmcnt).
      if (i < nk - 1) {
        if (md) asm volatile("s_waitcnt vmcnt(6)" ::: "memory");
        else    asm volatile("s_waitcnt vmcnt(4)" ::: "memory");
      } else {
        asm volatile("s_waitcnt vmcnt(0)" ::: "memory");
      }
      __builtin_amdgcn_s_barrier();          // buf i fully staged, all waves
      asm volatile("" ::: "memory");         // IR fence: no read hoists above

      const __hip_bfloat16* SA = S[i & 1][0];
      const __hip_bfloat16* SW = S[i & 1][1];
      const __hip_bfloat16* SX = S[i & 1][2];
      bf16x8 af[4], bw[4], xf[4];
#pragma unroll
      for (int fi = 0; fi < 4; fi++)
        af[fi] = frag_read(SA, wm + fi * 16 + r, g);
#pragma unroll
      for (int fj = 0; fj < 4; fj++)
        bw[fj] = frag_read(SW, wn + fj * 16 + r, g);
      if (md == 1) {
#pragma unroll
        for (int fi = 0; fi < 4; fi++)
          xf[fi] = frag_read(SX, wm + fi * 16 + r, g);
      } else if (md == 2) {
#pragma unroll
        for (int fj = 0; fj < 4; fj++)
          xf[fj] = frag_read(SX, wn + fj * 16 + r, g);
      }
      asm volatile("s_waitcnt lgkmcnt(0)" ::: "memory");  // my reads landed
      __builtin_amdgcn_sched_barrier(0);                  // rule 18
      __builtin_amdgcn_s_barrier();          // ALL waves done reading buf i
      asm volatile("" ::: "memory");         // IR fence: restage stays below

      if (i + 2 < nk) {                      // restage buf i for step i+2
        const long ko = kbeg + (long)(i + 2) * 32;
        stage256(A0 + ko, lda, S[i & 1][0], t);
        stage256(W0 + ko, ldb, S[i & 1][1], t);
        if (md) stage256(X0 + ko, xld, S[i & 1][2], t);
      }

#pragma unroll
      for (int fi = 0; fi < 4; fi++)
#pragma unroll
        for (int fj = 0; fj < 4; fj++)
          acc[fi][fj] = __builtin_amdgcn_mfma_f32_16x16x32_bf16(
              af[fi], bw[fj], acc[fi][fj], 0, 0, 0);
      if (md == 1) {
#pragma unroll
        for (int fi = 0; fi < 4; fi++)
#pragma unroll
          for (int fj = 0; fj < 4; fj++)
            acc[fi][fj] = __builtin_amdgcn_mfma_f32_16x16x32_bf16(
                xf[fi], bw[fj], acc[fi][fj], 0, 0, 0);
      } else if (md == 2) {
#pragma unroll
        for (int fi = 0; fi < 4; fi++)
#pragma unroll
          for (int fj = 0; fj < 4; fj++)
            acc[fi][fj] = __builtin_amdgcn_mfma_f32_16x16x32_bf16(
                af[fi], xf[fj], acc[fi][fj], 0, 0, 0);
      }
    }
    // Loop exit: all stages waited (vmcnt(0) at i=nk-1) -> clean for next rd.
  }

  if (ksplit > 1) {
    float* Cf = (float*)Cout + (long)kc * kslab;
#pragma unroll
    for (int fi = 0; fi < 4; fi++)
#pragma unroll
      for (int fj = 0; fj < 4; fj++)
#pragma unroll
        for (int v = 0; v < 4; v++) {
          int m = m0 + wm + fi * 16 + g * 4 + v;
          int n = n0 + wn + fj * 16 + r;
          long off = (long)bz * c_batch + (long)m * om + (long)(n >> 6) * oh + (n & 63);
          Cf[off] = acc[fi][fj][v];  // streaming partial, no RMW
        }
  } else {
#pragma unroll
    for (int fi = 0; fi < 4; fi++)
#pragma unroll
      for (int fj = 0; fj < 4; fj++)
#pragma unroll
        for (int v = 0; v < 4; v++) {
          int m = m0 + wm + fi * 16 + g * 4 + v;  // row = (lane>>4)*4 + reg
          int n = n0 + wn + fj * 16 + r;          // col = lane&15
          long off = (long)bz * c_batch + (long)m * om + (long)(n >> 6) * oh + (n & 63);
          float val = acc[fi][fj][v];
          if (bf) ((__hip_bfloat16*)Cout)[off] = __float2bfloat16(val);
          else    ((float*)Cout)[off] = val;
        }
  }
}

// ---------------------------------------------------------------------------
// Reduce 4 fp32 slabs -> Bmat fp32 + split-bf16 Bh/Bl. Vectorized x4.
// ---------------------------------------------------------------------------
__global__ __launch_bounds__(256) void reduce_split(
    const float* __restrict__ slabs, float* __restrict__ outf,
    __hip_bfloat16* __restrict__ dh, __hip_bfloat16* __restrict__ dl) {
  long i0 = ((long)blockIdx.x * 256 + threadIdx.x) * 4;
  f32x4 s = *(const f32x4*)(slabs + i0);
#pragma unroll
  for (int k = 1; k < 4; k++) {
    f32x4 v = *(const f32x4*)(slabs + (long)k * 1572864 + i0);
    s.x += v.x; s.y += v.y; s.z += v.z; s.w += v.w;
  }
  *(f32x4*)(outf + i0) = s;
#pragma unroll
  for (int j = 0; j < 4; j++) {
    float f = s[j];
    __hip_bfloat16 h = __float2bfloat16(f);
    dh[i0 + j] = h;
    dl[i0 + j] = __float2bfloat16(f - __bfloat162float(h));
  }
}

// ---------------------------------------------------------------------------
// Reduce 4 value-slabs [B,H,256,64] -> V^T split bf16 [B,H,64,256].
// ---------------------------------------------------------------------------
__global__ __launch_bounds__(256) void vtsplit_sum(
    const float* __restrict__ slabs, __hip_bfloat16* __restrict__ dh,
    __hip_bfloat16* __restrict__ dl) {
  __shared__ float tle[64][65];
  const int z = blockIdx.y;        // 96 = B*H
  const int r0 = blockIdx.x * 64;  // 4 row-tiles over n=256
  int cl = threadIdx.x & 63, rl4 = threadIdx.x >> 6;
#pragma unroll
  for (int i = 0; i < 16; i++) {
    int rr = rl4 + i * 4;
    long idx = (long)z * 16384 + (r0 + rr) * 64 + cl;
    float s = slabs[idx];
#pragma unroll
    for (int k = 1; k < 4; k++) s += slabs[(long)k * 1572864 + idx];
    tle[rr][cl] = s;
  }
  __syncthreads();
#pragma unroll
  for (int i = 0; i < 16; i++) {
    int cc = rl4 + i * 4;          // d index
    float f = tle[cl][cc];         // = V[n=r0+cl][d=cc]
    __hip_bfloat16 h = __float2bfloat16(f);
    long o = (long)z * 16384 + (long)cc * 256 + r0 + cl;
    dh[o] = h;
    dl[o] = __float2bfloat16(f - __bfloat162float(h));
  }
}

// ---------------------------------------------------------------------------
// bmu[b,d] = sum_n w_mu[n] * Bmat[n, b*768+d]   (and bsig with w_sigma)
// ---------------------------------------------------------------------------
__global__ __launch_bounds__(256) void bvec(
    const float* __restrict__ Bmat, const float* __restrict__ wmuf,
    const float* __restrict__ wsigf, float* __restrict__ bmu,
    float* __restrict__ bsig) {
  int t = blockIdx.x * 256 + threadIdx.x;
  int w = t / 6144, r = t % 6144;
  const float* wv = w ? wsigf : wmuf;
  float acc = 0.f;
  for (int n = 0; n < NB; n++) acc += wv[n] * Bmat[(long)n * 6144 + r];
  (w ? bsig : bmu)[r] = acc;
}

// kmu[b,c] = sum_d bmu[b,d] * Wk[c,d]   (c = h*64+dh), and ksig with bsig.
__global__ __launch_bounds__(256) void kvec(
    const float* __restrict__ Wkf, const float* __restrict__ bmu,
    const float* __restrict__ bsig, float* __restrict__ kmu,
    float* __restrict__ ksig) {
  int t = blockIdx.x * 256 + threadIdx.x;
  int w = t / 6144, r = t % 6144;
  int b = r / 768, c = r % 768;
  const float* bv = (w ? bsig : bmu) + b * 768;
  const float* wk = Wkf + (long)c * 768;
  float acc = 0.f;
  for (int d = 0; d < 768; d++) acc += bv[d] * wk[d];
  (w ? ksig : kmu)[r] = acc;
}

// wqm[b,h,d] = sum_dh Wq[h*64+dh, d] * kmu[b, h*64+dh]   (and wqs with ksig)
__global__ __launch_bounds__(256) void wqvec(
    const float* __restrict__ Wqf, const float* __restrict__ kmu,
    const float* __restrict__ ksig, float* __restrict__ wqm,
    float* __restrict__ wqs) {
  int t = blockIdx.x * 256 + threadIdx.x;
  int w = t / 73728, r = t % 73728;
  int b = r / 9216, h = (r % 9216) / 768, d = r % 768;
  const float* kv = (w ? ksig : kmu) + b * 768 + h * 64;
  float acc = 0.f;
  for (int dh = 0; dh < 64; dh++)
    acc += Wqf[(long)(h * 64 + dh) * 768 + d] * kv[dh];
  (w ? wqs : wqm)[r] = acc;
}

// ---------------------------------------------------------------------------
// amu[b, hh, qrow] = dot768(q[qrow, b, :], wq{m|s}[b, hh, :]); one wave/q-row.
// ---------------------------------------------------------------------------
__global__ __launch_bounds__(256) void amu_kernel(
    const void* __restrict__ q, const float* __restrict__ wqm,
    const float* __restrict__ wqs, float* __restrict__ amu,
    const int* __restrict__ flagp) {
  int bf = flagp[0];
  int lane = threadIdx.x & 63;
  int wave = threadIdx.x >> 6;
  int qrow = blockIdx.x * 4 + wave;
  int b = blockIdx.y;
  float qv[12];
  long base = ((long)qrow * 8 + b) * 768 + lane;
#pragma unroll
  for (int j = 0; j < 12; j++) qv[j] = gload(q, base + 64 * j, bf);
  for (int hh = 0; hh < 24; hh++) {
    const float* vec = (hh < 12) ? (wqm + ((long)b * 12 + hh) * 768)
                                 : (wqs + ((long)b * 12 + hh - 12) * 768);
    float p = 0.f;
#pragma unroll
    for (int j = 0; j < 12; j++) p += qv[j] * vec[lane + 64 * j];
#pragma unroll
    for (int m = 32; m >= 1; m >>= 1) p += __shfl_xor(p, m);
    if (lane == 0) amu[((long)b * 24 + hh) * 1024 + qrow] = p;
  }
}

// ---------------------------------------------------------------------------
// Fused MFMA attention: ctx[q,d] = sum_n r(q,n) * V[n,d] per (b,h).
// A = R computed in-register (split rh/rl), B = V^T (pre-split bf16 h/l).
// Wave tile: 32 q (fi=0,1) x 64 d (fj=0..3), K = 256 n in 8 k-steps.
// ---------------------------------------------------------------------------
__global__ __launch_bounds__(256) void attn_mfma(
    const __hip_bfloat16* __restrict__ Vth, const __hip_bfloat16* __restrict__ Vtl,
    const float* __restrict__ amu, const float* __restrict__ mubf,
    const float* __restrict__ sigbf, __hip_bfloat16* __restrict__ Ch,
    __hip_bfloat16* __restrict__ Cl) {
  const int qch = blockIdx.x, h = blockIdx.y, b = blockIdx.z;
  const int t = threadIdx.x;
  const int lane = t & 63, wave = t >> 6;
  const int r = lane & 15, g = lane >> 4;
  const int wq = wave * 32;
  __shared__ float s_mub[NB], s_sb2[NB];
  {
    float sb = sigbf[t];
    s_mub[t] = mubf[t];
    s_sb2[t] = sb * sb;
  }
  __syncthreads();

  float mu_[2], sig_[2];
#pragma unroll
  for (int fi = 0; fi < 2; fi++) {
    int q = qch * 128 + wq + fi * 16 + r;
    float araw = amu[((long)b * 24 + h) * 1024 + q] * 0.125f;
    float sraw = amu[((long)b * 24 + 12 + h) * 1024 + q] * 0.125f;
    mu_[fi] = 1.f / (1.f + expf(-araw));
    sig_[fi] = fmaxf(sraw, 0.f) + log1pf(expf(-fabsf(sraw)));  // softplus
  }

  const __hip_bfloat16* vhb = Vth + ((long)b * 12 + h) * 16384;
  const __hip_bfloat16* vlb = Vtl + ((long)b * 12 + h) * 16384;

  f32x4 zero4 = {0.f, 0.f, 0.f, 0.f};
  f32x4 acc[2][4];
#pragma unroll
  for (int fi = 0; fi < 2; fi++)
#pragma unroll
    for (int fj = 0; fj < 4; fj++) acc[fi][fj] = zero4;

  for (int ks = 0; ks < 8; ks++) {
    bf16x8 rh[2], rl[2];
#pragma unroll
    for (int fi = 0; fi < 2; fi++) {
      float mu = mu_[fi], sg = sig_[fi];
#pragma unroll
      for (int j = 0; j < 8; j++) {
        int n = ks * 32 + g * 8 + j;
        float inv_s = rsqrtf(s_sb2[n] + sg);
        float tt = (mu - s_mub[n]) * inv_s;
        float rv = 0.3989422804014327f * inv_s *
                   exp2f(-0.7213475204444817f * tt * tt);
        __bf16 hi = (__bf16)rv;
        rh[fi][j] = hi;
        rl[fi][j] = (__bf16)(rv - (float)hi);
      }
    }
#pragma unroll
    for (int fj = 0; fj < 4; fj++) {
      long vo = (long)(fj * 16 + r) * 256 + ks * 32 + g * 8;
      bf16x8 vh = *(const bf16x8*)(vhb + vo);
      bf16x8 vl = *(const bf16x8*)(vlb + vo);
#pragma unroll
      for (int fi = 0; fi < 2; fi++) {
        acc[fi][fj] = __builtin_amdgcn_mfma_f32_16x16x32_bf16(
            rh[fi], vh, acc[fi][fj], 0, 0, 0);
        acc[fi][fj] = __builtin_amdgcn_mfma_f32_16x16x32_bf16(
            rl[fi], vh, acc[fi][fj], 0, 0, 0);
        acc[fi][fj] = __builtin_amdgcn_mfma_f32_16x16x32_bf16(
            rh[fi], vl, acc[fi][fj], 0, 0, 0);
      }
    }
  }

#pragma unroll
  for (int fi = 0; fi < 2; fi++)
#pragma unroll
    for (int fj = 0; fj < 4; fj++)
#pragma unroll
      for (int v = 0; v < 4; v++) {
        int q = qch * 128 + wq + fi * 16 + g * 4 + v;  // row = (lane>>4)*4+reg
        int d = fj * 16 + r;                            // col = lane&15
        long off = ((long)(b * SLEN + q)) * DM + h * HEAD + d;
        float f = acc[fi][fj][v];
        __hip_bfloat16 hh = __float2bfloat16(f);
        Ch[off] = hh;
        Cl[off] = __float2bfloat16(f - __bfloat162float(hh));
      }
}

// ---------------------------------------------------------------------------
extern "C" void kernel_launch(void* const* d_in, const int* in_sizes, int n_in,
                              void* d_out, int out_size, void* d_ws, size_t ws_size,
                              hipStream_t stream) {
  const void* x    = d_in[0];
  const void* q    = d_in[1];
  const void* Wq   = d_in[2];
  const void* Wk   = d_in[3];
  const void* Wv   = d_in[4];
  const void* Wo   = d_in[5];
  const void* wmu  = d_in[6];
  const void* wsig = d_in[7];
  const void* mub  = d_in[8];
  const void* sigb = d_in[9];
  const void* G    = d_in[10];

  int* flagp = (int*)d_ws;
  float* base = (float*)d_ws + 16;
  float* Wqf   = base;              // 589824
  float* Wkf   = Wqf + 589824;      // 589824
  float* wmuf  = Wkf + 589824;      // 256
  float* wsigf = wmuf + 256;        // 256
  float* mubf  = wsigf + 256;       // 256
  float* sigbf = mubf + 256;        // 256
  float* Bmat  = sigbf + 256;       // 1572864  [256, 6144] fp32
  float* slab1 = Bmat + 1572864;    // 6291456  4x[256,6144] fp32 GEMM1 partials
  float* wqm   = slab1 + 6291456;   // 73728
  float* wqs   = wqm + 73728;       // 73728
  float* amu   = wqs + 73728;       // 196608  [B,24,1024]
  float* bmu   = amu + 196608;      // 6144
  float* bsig  = bmu + 6144;        // 6144
  float* kmu   = bsig + 6144;       // 6144
  float* ksig  = kmu + 6144;        // 6144
  // bf16 arrays (all 16B-aligned)
  __hip_bfloat16* Wvh = (__hip_bfloat16*)(ksig + 6144);   // 589824
  __hip_bfloat16* Wvl = Wvh + 589824;   // 589824
  __hip_bfloat16* Woh = Wvl + 589824;   // 589824
  __hip_bfloat16* Wol = Woh + 589824;   // 589824
  __hip_bfloat16* Gth = Wol + 589824;   // 262144  [256,1024]
  __hip_bfloat16* Gtl = Gth + 262144;   // 262144
  __hip_bfloat16* Bh  = Gtl + 262144;   // 1572864 [256,6144]
  __hip_bfloat16* Bl  = Bh + 1572864;   // 1572864
  // XCh/XCl region (25.2 MB) serves three consecutive roles:
  //   1) x^T split [6144,1024] for GEMM1
  //   2) GEMM2 fp32 partial slabs 4x[B,H,256,64] (= exactly 6291456 floats)
  //   3) ctx split-bf16 [8192,768] written by attn for GEMM3
  __hip_bfloat16* XCh = Bl + 1572864;   // 6291456
  __hip_bfloat16* XCl = XCh + 6291456;  // 6291456
  float* slab2 = (float*)XCh;           // alias, role 2
  __hip_bfloat16* Vth = XCl + 6291456;  // 1572864 [B,H,64,256] split V^T
  __hip_bfloat16* Vtl = Vth + 1572864;  // 1572864
  // total ~81 MB

  detect_dtype<<<1, 256, 0, stream>>>(x, flagp);

  // All independent preprocessing in one dispatch.
  prep<<<3908, 256, 0, stream>>>(
      Wq, Wk, wmu, wsig, mub, sigb, G, x, Wv, Wo,
      Wqf, Wkf, wmuf, wsigf, mubf, sigbf,
      Gth, Gtl, XCh, XCl, Wvh, Wvl, Woh, Wol, flagp);

  // GEMM1: Bmat = G^T @ x^T'; M=256 N=6144 K=1024. ksplit=4 streamed slabs.
  mfma_nt_lds<<<dim3(48, 2, 4), 256, 0, stream>>>(
      Gth, Gtl, XCh, XCl, slab1, /*K=*/1024, /*lda=*/1024, /*ldb=*/1024,
      /*a_batch=*/0, /*c_batch=*/0, /*om=*/6144, /*oh=*/64, flagp, 0,
      /*pmask_bf=*/1, /*ksplit=*/4, /*kslab=*/1572864);

  // slabs -> Bmat fp32 + Bh/Bl split (one pass).
  reduce_split<<<1536, 256, 0, stream>>>(slab1, Bmat, Bh, Bl);

  // GEMM2: values(z) = Bmat_z @ Wv^T; ksplit=4 streamed slabs (into XC region;
  // x^T is dead after GEMM1).
  mfma_nt_lds<<<dim3(6, 2, 32), 256, 0, stream>>>(
      Bh, Bl, Wvh, Wvl, slab2, /*K=*/768, /*lda=*/6144, /*ldb=*/768,
      /*a_batch=*/768, /*c_batch=*/196608, /*om=*/64, /*oh=*/16384, flagp, 0,
      /*pmask_bf=*/5, /*ksplit=*/4, /*kslab=*/1572864);

  // slabs -> V^T split (one pass; fp32 values never materialized).
  vtsplit_sum<<<dim3(4, 96), 256, 0, stream>>>(slab2, Vth, Vtl);

  // collapse chain as 3 separate well-parallelized kernels (48/48/576 blocks;
  // the 16-block fused version was a 380 µs occupancy disaster — R6).
  bvec<<<48, 256, 0, stream>>>(Bmat, wmuf, wsigf, bmu, bsig);
  kvec<<<48, 256, 0, stream>>>(Wkf, bmu, bsig, kmu, ksig);
  wqvec<<<576, 256, 0, stream>>>(Wqf, kmu, ksig, wqm, wqs);
  amu_kernel<<<dim3(256, 8), 256, 0, stream>>>(q, wqm, wqs, amu, flagp);

  // fused MFMA attention -> ctx split-bf16 [8192,768] (into XCh/XCl; slab2
  // already consumed by vtsplit_sum).
  attn_mfma<<<dim3(8, 12, 8), 256, 0, stream>>>(
      Vth, Vtl, amu, mubf, sigbf, XCh, XCl);

  // GEMM3: out = ctx @ Wo^T; M=8192 N=768 K=768; direct store (dtype per flag).
  mfma_nt_lds<<<dim3(6, 64, 1), 256, 0, stream>>>(
      XCh, XCl, Woh, Wol, d_out, /*K=*/768, /*lda=*/768, /*ldb=*/768,
      /*a_batch=*/0, /*c_batch=*/0, /*om=*/768, /*oh=*/64, flagp, 1,
      /*pmask_bf=*/5, /*ksplit=*/1, /*kslab=*/0);
}